// Round 1
// baseline (567.823 us; speedup 1.0000x reference)
//
#include <hip/hip_runtime.h>
#include <hip/hip_bf16.h>

#define N_NODES 50000
#define N_EDGES 800000
#define HEADS 8
#define CPH 16          // channels per head
#define DIM 128         // HEADS*CPH == IN_DIM == OUT_DIM
#define NEG_SLOPE 0.2f
#define EPS 1e-16f

// ---------------------------------------------------------------------------
// Kernel 1: h = x @ W   (50000x128 · 128x128, fp32 vector ALU)
// Tile: 64 rows/block, 256 threads, each thread 8 rows x 4 cols.
// x tile stored TRANSPOSED in LDS (xs[k][row]) with pad so per-k reads are
// two ds_read_b128 broadcasts per lane group.
// ---------------------------------------------------------------------------
__global__ __launch_bounds__(256) void k_gemm(const float* __restrict__ x,
                                              const float* __restrict__ W,
                                              float* __restrict__ h) {
    constexpr int LDT = 68;                 // padded row stride (floats), 68%4==0, bank-safe
    __shared__ float xs[128 * LDT];         // 34.8 KB
    const int row0 = blockIdx.x * 64;
    const int tid = threadIdx.x;

    // Load 64 rows x 128 cols of x (float4), store transposed xs[k][r]
    for (int i = tid; i < 64 * 32; i += 256) {
        const int r = i >> 5;               // 0..63
        const int k4 = i & 31;              // 0..31 (float4 index along k)
        const int row = row0 + r;
        float4 v = make_float4(0.f, 0.f, 0.f, 0.f);
        if (row < N_NODES) v = ((const float4*)x)[row * 32 + k4];
        const int k = k4 * 4;
        xs[(k + 0) * LDT + r] = v.x;
        xs[(k + 1) * LDT + r] = v.y;
        xs[(k + 2) * LDT + r] = v.z;
        xs[(k + 3) * LDT + r] = v.w;
    }
    __syncthreads();

    const int colg = tid & 31;              // cols colg*4 .. +3
    const int rowg = tid >> 5;              // rows rowg*8 .. +7
    float acc[8][4];
#pragma unroll
    for (int r = 0; r < 8; ++r)
#pragma unroll
        for (int j = 0; j < 4; ++j) acc[r][j] = 0.f;

    for (int k = 0; k < 128; ++k) {
        const float4 w = ((const float4*)W)[k * 32 + colg];
        const float* xr = xs + k * LDT + rowg * 8;
        const float4 xa = *(const float4*)(xr);
        const float4 xb = *(const float4*)(xr + 4);
        const float xv[8] = {xa.x, xa.y, xa.z, xa.w, xb.x, xb.y, xb.z, xb.w};
        const float wv[4] = {w.x, w.y, w.z, w.w};
#pragma unroll
        for (int r = 0; r < 8; ++r)
#pragma unroll
            for (int j = 0; j < 4; ++j) acc[r][j] += xv[r] * wv[j];
    }

#pragma unroll
    for (int r = 0; r < 8; ++r) {
        const int row = row0 + rowg * 8 + r;
        if (row < N_NODES)
            ((float4*)h)[row * 32 + colg] =
                make_float4(acc[r][0], acc[r][1], acc[r][2], acc[r][3]);
    }
}

// ---------------------------------------------------------------------------
// Kernel 2: a_src[n,h] = <h[n,h,:], att_src[h,:]>, same for a_dst
// One thread per (n, head). h + t*16 is the per-(n,head) 16-float segment.
// ---------------------------------------------------------------------------
__global__ __launch_bounds__(256) void k_att(const float* __restrict__ h,
                                             const float* __restrict__ att_s,
                                             const float* __restrict__ att_d,
                                             float* __restrict__ asrc,
                                             float* __restrict__ adst) {
    const int t = blockIdx.x * 256 + threadIdx.x;
    if (t >= N_NODES * HEADS) return;
    const int hd = t & 7;
    const float4* hp = (const float4*)h + t * 4;
    const float4* as4 = (const float4*)att_s + hd * 4;
    const float4* ad4 = (const float4*)att_d + hd * 4;
    float ss = 0.f, sd = 0.f;
#pragma unroll
    for (int i = 0; i < 4; ++i) {
        const float4 hv = hp[i];
        const float4 av = as4[i];
        const float4 dv = ad4[i];
        ss += hv.x * av.x + hv.y * av.y + hv.z * av.z + hv.w * av.w;
        sd += hv.x * dv.x + hv.y * dv.y + hv.z * dv.z + hv.w * dv.w;
    }
    asrc[t] = ss;
    adst[t] = sd;
}

// ---------------------------------------------------------------------------
// Kernel 3: self-loop init. denom[n,h] = exp(lrelu(a_src[n,h]+a_dst[n,h]));
// out_raw[n,c] = denom_val * h[n,c].  Also serves as the initializer for the
// atomic accumulators (d_ws/d_out are poisoned before every call).
// ---------------------------------------------------------------------------
__global__ __launch_bounds__(256) void k_init(const float* __restrict__ h,
                                              const float* __restrict__ asrc,
                                              const float* __restrict__ adst,
                                              float* __restrict__ denom,
                                              float* __restrict__ outr) {
    const int t = blockIdx.x * 256 + threadIdx.x;
    if (t >= N_NODES * DIM) return;
    const int n = t >> 7;
    const int c = t & 127;
    const int hd = c >> 4;
    float e = asrc[n * 8 + hd] + adst[n * 8 + hd];
    e = (e >= 0.f) ? e : NEG_SLOPE * e;
    const float ex = __expf(e);
    outr[t] = ex * h[t];
    if ((c & 15) == 0) denom[n * 8 + hd] = ex;
}

// ---------------------------------------------------------------------------
// Kernel 4: fused edge pass. One thread per (edge, channel).
// ex = exp(lrelu(a_src[src,h] + a_dst[dst,h]))
// out_raw[dst,c] += ex * h[src,c]   (atomic)
// denom[dst,h]   += ex              (atomic, one lane per head)
// No max-subtraction: e is O(±10), exp safely in fp32 range; normalization
// by (denom+eps) at the end is algebraically identical to per-edge alpha.
// ---------------------------------------------------------------------------
__global__ __launch_bounds__(256) void k_edge(const int* __restrict__ ei,
                                              const float* __restrict__ h,
                                              const float* __restrict__ asrc,
                                              const float* __restrict__ adst,
                                              float* __restrict__ denom,
                                              float* __restrict__ outr) {
    const int t = blockIdx.x * 256 + threadIdx.x;
    const int edge = t >> 7;
    if (edge >= N_EDGES) return;
    const int c = t & 127;
    const int hd = c >> 4;
    const int s = ei[edge];
    const int d = ei[N_EDGES + edge];
    float e = asrc[s * 8 + hd] + adst[d * 8 + hd];
    e = (e >= 0.f) ? e : NEG_SLOPE * e;
    const float ex = __expf(e);
    atomicAdd(&outr[d * 128 + c], ex * h[s * 128 + c]);
    if ((c & 15) == 0) atomicAdd(&denom[d * 8 + hd], ex);
}

// ---------------------------------------------------------------------------
// Kernel 5: out = elu(out_raw / (denom + eps) + bias)
// ---------------------------------------------------------------------------
__global__ __launch_bounds__(256) void k_final(float* __restrict__ out,
                                               const float* __restrict__ denom,
                                               const float* __restrict__ bias) {
    const int t = blockIdx.x * 256 + threadIdx.x;
    if (t >= N_NODES * DIM) return;
    const int n = t >> 7;
    const int c = t & 127;
    const int hd = c >> 4;
    const float v = out[t] / (denom[n * 8 + hd] + EPS) + bias[c];
    out[t] = (v > 0.f) ? v : expm1f(v);
}

extern "C" void kernel_launch(void* const* d_in, const int* in_sizes, int n_in,
                              void* d_out, int out_size, void* d_ws, size_t ws_size,
                              hipStream_t stream) {
    const float* x     = (const float*)d_in[0];
    const int*   ei    = (const int*)d_in[1];
    const float* W     = (const float*)d_in[2];
    const float* att_s = (const float*)d_in[3];
    const float* att_d = (const float*)d_in[4];
    const float* bias  = (const float*)d_in[5];
    float* out = (float*)d_out;

    // workspace layout (30.4 MB total)
    float* h     = (float*)d_ws;                       // 50000*128 = 25.6 MB
    float* asrc  = h + (size_t)N_NODES * DIM;          // 1.6 MB
    float* adst  = asrc + (size_t)N_NODES * HEADS;     // 1.6 MB
    float* denom = adst + (size_t)N_NODES * HEADS;     // 1.6 MB

    k_gemm<<<(N_NODES + 63) / 64, 256, 0, stream>>>(x, W, h);
    k_att<<<(N_NODES * HEADS + 255) / 256, 256, 0, stream>>>(h, att_s, att_d, asrc, adst);
    k_init<<<(N_NODES * DIM + 255) / 256, 256, 0, stream>>>(h, asrc, adst, denom, out);
    k_edge<<<(N_EDGES * DIM) / 256, 256, 0, stream>>>(ei, h, asrc, adst, denom, out);
    k_final<<<(N_NODES * DIM + 255) / 256, 256, 0, stream>>>(out, denom, bias);
}

// Round 2
// 262.246 us; speedup vs baseline: 2.1652x; 2.1652x over previous
//
#include <hip/hip_runtime.h>
#include <hip/hip_bf16.h>

#define N_NODES 50000
#define N_EDGES 800000
#define HEADS 8
#define CPH 16
#define DIM 128
#define NEG_SLOPE 0.2f
#define EPS 1e-16f
#define NB1 ((N_NODES + 255) / 256)   // 196 scan blocks

// ---------------------------------------------------------------------------
// Kernel 1: h = x @ W   (50000x128 · 128x128, fp32 vector ALU) — unchanged.
// ---------------------------------------------------------------------------
__global__ __launch_bounds__(256) void k_gemm(const float* __restrict__ x,
                                              const float* __restrict__ W,
                                              float* __restrict__ h) {
    constexpr int LDT = 68;
    __shared__ float xs[128 * LDT];
    const int row0 = blockIdx.x * 64;
    const int tid = threadIdx.x;

    for (int i = tid; i < 64 * 32; i += 256) {
        const int r = i >> 5;
        const int k4 = i & 31;
        const int row = row0 + r;
        float4 v = make_float4(0.f, 0.f, 0.f, 0.f);
        if (row < N_NODES) v = ((const float4*)x)[row * 32 + k4];
        const int k = k4 * 4;
        xs[(k + 0) * LDT + r] = v.x;
        xs[(k + 1) * LDT + r] = v.y;
        xs[(k + 2) * LDT + r] = v.z;
        xs[(k + 3) * LDT + r] = v.w;
    }
    __syncthreads();

    const int colg = tid & 31;
    const int rowg = tid >> 5;
    float acc[8][4];
#pragma unroll
    for (int r = 0; r < 8; ++r)
#pragma unroll
        for (int j = 0; j < 4; ++j) acc[r][j] = 0.f;

    for (int k = 0; k < 128; ++k) {
        const float4 w = ((const float4*)W)[k * 32 + colg];
        const float* xr = xs + k * LDT + rowg * 8;
        const float4 xa = *(const float4*)(xr);
        const float4 xb = *(const float4*)(xr + 4);
        const float xv[8] = {xa.x, xa.y, xa.z, xa.w, xb.x, xb.y, xb.z, xb.w};
        const float wv[4] = {w.x, w.y, w.z, w.w};
#pragma unroll
        for (int r = 0; r < 8; ++r)
#pragma unroll
            for (int j = 0; j < 4; ++j) acc[r][j] += xv[r] * wv[j];
    }

#pragma unroll
    for (int r = 0; r < 8; ++r) {
        const int row = row0 + rowg * 8 + r;
        if (row < N_NODES)
            ((float4*)h)[row * 32 + colg] =
                make_float4(acc[r][0], acc[r][1], acc[r][2], acc[r][3]);
    }
}

// ---------------------------------------------------------------------------
// CSR build: histogram of destination degrees.
// ---------------------------------------------------------------------------
__global__ __launch_bounds__(256) void k_hist(const int* __restrict__ ei,
                                              int* __restrict__ deg) {
    const int t = blockIdx.x * 256 + threadIdx.x;
    if (t < N_EDGES) atomicAdd(&deg[ei[N_EDGES + t]], 1);
}

// Exclusive scan, phase 1: per-block (256-wide) scan + block totals.
__global__ __launch_bounds__(256) void k_scan1(const int* __restrict__ deg,
                                               int* __restrict__ rowptr,
                                               int* __restrict__ partials) {
    __shared__ int sh[256];
    const int tid = threadIdx.x;
    const int i = blockIdx.x * 256 + tid;
    const int v = (i < N_NODES) ? deg[i] : 0;
    sh[tid] = v;
    __syncthreads();
#pragma unroll
    for (int off = 1; off < 256; off <<= 1) {
        const int t2 = (tid >= off) ? sh[tid - off] : 0;
        __syncthreads();
        sh[tid] += t2;
        __syncthreads();
    }
    if (i < N_NODES) rowptr[i] = sh[tid] - v;      // exclusive within block
    if (tid == 255) partials[blockIdx.x] = sh[255];
}

// Phase 2: single block scans the block totals (in place, exclusive).
__global__ __launch_bounds__(256) void k_scan2(int* __restrict__ partials) {
    __shared__ int sh[256];
    const int tid = threadIdx.x;
    const int v = (tid < NB1) ? partials[tid] : 0;
    sh[tid] = v;
    __syncthreads();
#pragma unroll
    for (int off = 1; off < 256; off <<= 1) {
        const int t2 = (tid >= off) ? sh[tid - off] : 0;
        __syncthreads();
        sh[tid] += t2;
        __syncthreads();
    }
    if (tid < NB1) partials[tid] = sh[tid] - v;
}

// Phase 3: add block offsets; init cursor = rowptr.
__global__ __launch_bounds__(256) void k_scan3(const int* __restrict__ partials,
                                               int* __restrict__ rowptr,
                                               int* __restrict__ cursor) {
    const int i = blockIdx.x * 256 + threadIdx.x;
    if (i < N_NODES) {
        const int r = rowptr[i] + partials[blockIdx.x];
        rowptr[i] = r;
        cursor[i] = r;
    }
}

// Scatter: place src id of each edge into its dst segment.
// After this kernel, cursor[d] == end of segment d.
__global__ __launch_bounds__(256) void k_scatter(const int* __restrict__ ei,
                                                 int* __restrict__ cursor,
                                                 int* __restrict__ srcs) {
    const int t = blockIdx.x * 256 + threadIdx.x;
    if (t < N_EDGES) {
        const int d = ei[N_EDGES + t];
        const int pos = atomicAdd(&cursor[d], 1);
        srcs[pos] = ei[t];
    }
}

// ---------------------------------------------------------------------------
// Aggregate: one wave (64 threads) per destination node; thread owns 2
// channels (float2). Attention logits computed in-register:
//   a_dst[d] once per block, a_src[s] per edge via 3-step 8-lane butterfly
//   (h[s] is loaded anyway for the message — logits are free of mem traffic).
// Self-loop, denom, bias, ELU all folded in. Zero atomics. One write.
// ---------------------------------------------------------------------------
__global__ __launch_bounds__(64) void k_aggr(const float* __restrict__ h,
                                             const int* __restrict__ srcs,
                                             const int* __restrict__ rowptr,
                                             const int* __restrict__ cursor,
                                             const float* __restrict__ att_s,
                                             const float* __restrict__ att_d,
                                             const float* __restrict__ bias,
                                             float* __restrict__ out) {
    const int d = blockIdx.x;
    const int lane = threadIdx.x;           // 0..63, channels 2*lane, 2*lane+1
    const float2 as = ((const float2*)att_s)[lane];
    const float2 ad = ((const float2*)att_d)[lane];
    const float2 hd_v = ((const float2*)h)[d * 64 + lane];

    // block-level: a_dst(d) and a_src(d) (for the self loop)
    float pd = hd_v.x * ad.x + hd_v.y * ad.y;
    float ps = hd_v.x * as.x + hd_v.y * as.y;
#pragma unroll
    for (int m = 1; m < 8; m <<= 1) {
        pd += __shfl_xor(pd, m, 64);
        ps += __shfl_xor(ps, m, 64);
    }
    const float adst_d = pd;
    float es = ps + adst_d;
    es = (es >= 0.f) ? es : NEG_SLOPE * es;
    const float exs = __expf(es);

    float2 acc = make_float2(0.f, 0.f);
    float den = 0.f;

    int j = rowptr[d];
    const int jend = cursor[d];
    float2 hv_next = make_float2(0.f, 0.f);
    if (j < jend) {
        const int s0 = srcs[j];
        hv_next = ((const float2*)h)[s0 * 64 + lane];
    }
    while (j < jend) {
        const float2 hv = hv_next;
        ++j;
        if (j < jend) {
            const int sn = srcs[j];
            hv_next = ((const float2*)h)[sn * 64 + lane];   // prefetch next
        }
        float p = hv.x * as.x + hv.y * as.y;
#pragma unroll
        for (int m = 1; m < 8; m <<= 1) p += __shfl_xor(p, m, 64);
        float e = p + adst_d;
        e = (e >= 0.f) ? e : NEG_SLOPE * e;
        const float ex = __expf(e);
        acc.x += ex * hv.x;
        acc.y += ex * hv.y;
        den += ex;
    }

    const float dtot = den + exs + EPS;
    const float2 b2 = ((const float2*)bias)[lane];
    float vx = (acc.x + exs * hd_v.x) / dtot + b2.x;
    float vy = (acc.y + exs * hd_v.y) / dtot + b2.y;
    vx = (vx > 0.f) ? vx : expm1f(vx);
    vy = (vy > 0.f) ? vy : expm1f(vy);
    ((float2*)out)[d * 64 + lane] = make_float2(vx, vy);
}

extern "C" void kernel_launch(void* const* d_in, const int* in_sizes, int n_in,
                              void* d_out, int out_size, void* d_ws, size_t ws_size,
                              hipStream_t stream) {
    const float* x     = (const float*)d_in[0];
    const int*   ei    = (const int*)d_in[1];
    const float* W     = (const float*)d_in[2];
    const float* att_s = (const float*)d_in[3];
    const float* att_d = (const float*)d_in[4];
    const float* bias  = (const float*)d_in[5];
    float* out = (float*)d_out;

    // workspace layout (~29.4 MB)
    float* h       = (float*)d_ws;                         // 25.6 MB
    int*   srcs    = (int*)(h + (size_t)N_NODES * DIM);    // 3.2 MB
    int*   rowptr  = srcs + N_EDGES;                       // 200 KB
    int*   cursor  = rowptr + N_NODES;                     // 200 KB
    int*   deg     = cursor + N_NODES;                     // 200 KB
    int*   partials= deg + N_NODES;                        // 1 KB

    hipMemsetAsync(deg, 0, N_NODES * sizeof(int), stream);

    k_gemm<<<(N_NODES + 63) / 64, 256, 0, stream>>>(x, W, h);
    k_hist<<<(N_EDGES + 255) / 256, 256, 0, stream>>>(ei, deg);
    k_scan1<<<NB1, 256, 0, stream>>>(deg, rowptr, partials);
    k_scan2<<<1, 256, 0, stream>>>(partials);
    k_scan3<<<NB1, 256, 0, stream>>>(partials, rowptr, cursor);
    k_scatter<<<(N_EDGES + 255) / 256, 256, 0, stream>>>(ei, cursor, srcs);
    k_aggr<<<N_NODES, 64, 0, stream>>>(h, srcs, rowptr, cursor,
                                       att_s, att_d, bias, out);
}